// Round 3
// baseline (1255.199 us; speedup 1.0000x reference)
//
#include <hip/hip_runtime.h>
#include <math.h>

#define NODES_PER_BUCKET 64
#define BUCKET_SHIFT 6
#define MAXNB 1600
#define BIN_CHUNK 8192

__device__ __forceinline__ unsigned short f2bf(float f){
  unsigned int u = __float_as_uint(f);
  unsigned int r = (u + 0x7FFFu + ((u >> 16) & 1u)) >> 16;   // RNE
  return (unsigned short)r;
}
__device__ __forceinline__ float bf2f(unsigned short b){
  return __uint_as_float(((unsigned int)b) << 16);
}

// ---------------- setup ----------------

__global__ void k_zero(int* __restrict__ p, int n){
  int i = blockIdx.x*256 + threadIdx.x;
  if(i < n) p[i] = 0;
}

__global__ void k_hist(const int* __restrict__ dst, int E, int* __restrict__ cnt){
  int i = blockIdx.x*256 + threadIdx.x;
  if(i < E) atomicAdd(&cnt[dst[i]], 1);
}

__global__ void k_dinv(const int* __restrict__ cnt, float* __restrict__ dinv, int n){
  int i = blockIdx.x*256 + threadIdx.x;
  if(i < n) dinv[i] = 1.0f / sqrtf((float)(cnt[i] + 1));  // +1 self loop => deg>=1
}

// bucket counts = sum of 64 per-node counts
__global__ void k_bsum(const int* __restrict__ cnt, int* __restrict__ bcnt, int N, int NB){
  int b = blockIdx.x*256 + threadIdx.x;
  if(b < NB){
    int base = b << BUCKET_SHIFT;
    int e = base + NODES_PER_BUCKET; if(e > N) e = N;
    int s = 0;
    for(int i = base; i < e; i++) s += cnt[i];
    bcnt[b] = s;
  }
}

// single-block scan over NB (<=2048) bucket counts -> bofs (exclusive), bcur
__global__ void k_bscan(const int* __restrict__ bcnt, int* __restrict__ bofs,
                        int* __restrict__ bcur, int NB, int E){
  __shared__ int sh[1024];
  int t = threadIdx.x;
  int c0 = (2*t   < NB) ? bcnt[2*t]   : 0;
  int c1 = (2*t+1 < NB) ? bcnt[2*t+1] : 0;
  sh[t] = c0 + c1; __syncthreads();
  for(int off = 1; off < 1024; off <<= 1){
    int v = (t >= off) ? sh[t - off] : 0;
    __syncthreads();
    sh[t] += v;
    __syncthreads();
  }
  int pairEx = sh[t] - (c0 + c1);
  if(2*t   < NB){ bofs[2*t]   = pairEx;      bcur[2*t]   = pairEx; }
  if(2*t+1 < NB){ bofs[2*t+1] = pairEx + c0; bcur[2*t+1] = pairEx + c0; }
  if(t == 0) bofs[NB] = E;
}

// LDS-staged binning: per-block LDS histogram -> one range-reservation atomic
// per (block,bucket) -> burst writes. Kills the 1.6M-on-1563 global atomic
// serialization of the previous version.
__global__ __launch_bounds__(256) void k_binpass(const int* __restrict__ src,
                          const int* __restrict__ dst, int E,
                          int* __restrict__ bcur, unsigned int* __restrict__ binned, int NB){
  __shared__ int lcnt[MAXNB];
  __shared__ int lpos[MAXNB];
  int t = threadIdx.x;
  int base = blockIdx.x * BIN_CHUNK;
  int end = base + BIN_CHUNK; if(end > E) end = E;
  for(int b = t; b < NB; b += 256) lcnt[b] = 0;
  __syncthreads();
  for(int i = base + t; i < end; i += 256)
    atomicAdd(&lcnt[dst[i] >> BUCKET_SHIFT], 1);
  __syncthreads();
  for(int b = t; b < NB; b += 256){
    int c = lcnt[b];
    lpos[b] = c ? atomicAdd(&bcur[b], c) : 0;
  }
  __syncthreads();
  for(int i = base + t; i < end; i += 256){
    int d = dst[i];
    int b = d >> BUCKET_SHIFT;
    unsigned int rec = (unsigned int)src[i] | ((unsigned int)(d & (NODES_PER_BUCKET-1)) << 17);
    int p = atomicAdd(&lpos[b], 1);
    binned[p] = rec;
  }
}

// ---------------- GEMM1: g1 = bf16( dinv * (x @ W1) ) ----------------
__global__ __launch_bounds__(256) void k_gemm1(const float* __restrict__ x, const float* __restrict__ W1,
                        const float* __restrict__ dinv, unsigned short* __restrict__ g1, int n){
  __shared__ float xs[64*128];
  __shared__ float ws[128*64];
  int tid = threadIdx.x;
  int nodeBase = blockIdx.x*64;
  {
    const float4* w4 = (const float4*)W1;
    float4* s4 = (float4*)ws;
    for(int i = tid; i < 2048; i += 256) s4[i] = w4[i];
  }
  {
    const float4* x4 = (const float4*)x;
    float4* s4 = (float4*)xs;
    for(int i = tid; i < 2048; i += 256){
      int node = i >> 5, kg = i & 31;
      float4 v = make_float4(0.f,0.f,0.f,0.f);
      if(nodeBase + node < n) v = x4[(size_t)(nodeBase + node)*32 + kg];
      s4[i] = v;
    }
  }
  __syncthreads();
  int tx = tid & 7, ty = tid >> 3;
  int n0 = ty*2, f0 = tx*8;
  float acc[2][8];
  #pragma unroll
  for(int i = 0; i < 2; i++)
    #pragma unroll
    for(int j = 0; j < 8; j++) acc[i][j] = 0.f;

  #pragma unroll 4
  for(int k = 0; k < 128; k++){
    float a0 = xs[(n0+0)*128 + k];
    float a1 = xs[(n0+1)*128 + k];
    float4 b0 = *(const float4*)&ws[k*64 + f0];
    float4 b1 = *(const float4*)&ws[k*64 + f0 + 4];
    acc[0][0] += a0*b0.x; acc[0][1] += a0*b0.y; acc[0][2] += a0*b0.z; acc[0][3] += a0*b0.w;
    acc[0][4] += a0*b1.x; acc[0][5] += a0*b1.y; acc[0][6] += a0*b1.z; acc[0][7] += a0*b1.w;
    acc[1][0] += a1*b0.x; acc[1][1] += a1*b0.y; acc[1][2] += a1*b0.z; acc[1][3] += a1*b0.w;
    acc[1][4] += a1*b1.x; acc[1][5] += a1*b1.y; acc[1][6] += a1*b1.z; acc[1][7] += a1*b1.w;
  }
  #pragma unroll
  for(int i = 0; i < 2; i++){
    int node = nodeBase + n0 + i;
    if(node < n){
      float dv = dinv[node];
      union { unsigned short us[8]; uint4 u4; } pk;
      #pragma unroll
      for(int j = 0; j < 8; j++) pk.us[j] = f2bf(acc[i][j]*dv);
      *(uint4*)&g1[(size_t)node*64 + f0] = pk.u4;
    }
  }
}

// ---------------- agg1: one block per bucket, LDS fp32 accumulators ----------------
// out1 = relu(dinv[d]*(g1[d] + sum g1[src]) + b1)
__global__ __launch_bounds__(256) void k_agg1(const unsigned short* __restrict__ g1,
    const int* __restrict__ bofs, const unsigned int* __restrict__ binned,
    const float* __restrict__ dinv, const float* __restrict__ b1,
    float* __restrict__ out1, int N){
  __shared__ float acc[64*64];   // 16 KB
  int t = threadIdx.x, lane = t & 63, wid = t >> 6;
  int b = blockIdx.x;
  {
    float4* a4 = (float4*)acc;
    for(int i = t; i < 1024; i += 256) a4[i] = make_float4(0.f,0.f,0.f,0.f);
  }
  __syncthreads();
  int beg = bofs[b], end = bofs[b+1];
  int e = beg + wid;
  for(; e + 4 < end; e += 8){
    unsigned int r0 = binned[e], r1 = binned[e+4];
    float v0 = bf2f(g1[(size_t)(r0 & 0x1FFFFu)*64 + lane]);
    float v1 = bf2f(g1[(size_t)(r1 & 0x1FFFFu)*64 + lane]);
    atomicAdd(&acc[(r0 >> 17)*64 + lane], v0);
    atomicAdd(&acc[(r1 >> 17)*64 + lane], v1);
  }
  if(e < end){
    unsigned int r0 = binned[e];
    float v0 = bf2f(g1[(size_t)(r0 & 0x1FFFFu)*64 + lane]);
    atomicAdd(&acc[(r0 >> 17)*64 + lane], v0);
  }
  __syncthreads();
  int nodeBase = b << BUCKET_SHIFT;
  for(int r = wid; r < 64; r += 4){
    int node = nodeBase + r;
    if(node < N){
      float self = bf2f(g1[(size_t)node*64 + lane]);
      float v = dinv[node]*(acc[r*64 + lane] + self) + b1[lane];
      out1[(size_t)node*64 + lane] = fmaxf(v, 0.f);
    }
  }
}

// ---------------- GEMM2: g2 = bf16( dinv * (out1 @ W2) ), 64-node LDS tile ----------------
__global__ __launch_bounds__(256) void k_gemm2(const float* __restrict__ h, const float* __restrict__ W2,
                        const float* __restrict__ dinv, unsigned short* __restrict__ g2, int n){
  __shared__ float hs[64*65];   // stride 65: a-reads conflict-free
  __shared__ float ws[64*40];
  int t = threadIdx.x;
  int nodeBase = blockIdx.x*64;
  for(int i = t; i < 2560; i += 256) ws[i] = W2[i];
  {
    const float4* h4 = (const float4*)h;
    for(int i = t; i < 1024; i += 256){
      int nl = i >> 4, kg = i & 15;
      float4 v = make_float4(0.f,0.f,0.f,0.f);
      if(nodeBase + nl < n) v = h4[(size_t)(nodeBase + nl)*16 + kg];
      float* dp = &hs[nl*65 + kg*4];
      dp[0] = v.x; dp[1] = v.y; dp[2] = v.z; dp[3] = v.w;
    }
  }
  __syncthreads();
  int tn = t >> 3, tf = t & 7;          // 32 node-pairs x 8 class-groups(5)
  int n0 = tn*2, f0 = tf*5;
  float a2[2][5] = {{0.f,0.f,0.f,0.f,0.f},{0.f,0.f,0.f,0.f,0.f}};
  #pragma unroll 4
  for(int k = 0; k < 64; k++){
    float a0 = hs[(n0+0)*65 + k];
    float a1 = hs[(n0+1)*65 + k];
    float w0 = ws[k*40+f0+0], w1 = ws[k*40+f0+1], w2 = ws[k*40+f0+2],
          w3 = ws[k*40+f0+3], w4 = ws[k*40+f0+4];
    a2[0][0]+=a0*w0; a2[0][1]+=a0*w1; a2[0][2]+=a0*w2; a2[0][3]+=a0*w3; a2[0][4]+=a0*w4;
    a2[1][0]+=a1*w0; a2[1][1]+=a1*w1; a2[1][2]+=a1*w2; a2[1][3]+=a1*w3; a2[1][4]+=a1*w4;
  }
  #pragma unroll
  for(int i = 0; i < 2; i++){
    int node = nodeBase + n0 + i;
    if(node < n){
      float dv = dinv[node];
      #pragma unroll
      for(int j = 0; j < 5; j++)
        g2[(size_t)node*40 + f0 + j] = f2bf(a2[i][j]*dv);
    }
  }
}

// ---------------- agg2: bucket LDS accumulate + bias + log_softmax ----------------
__global__ __launch_bounds__(256) void k_agg2(const unsigned short* __restrict__ g2,
     const int* __restrict__ bofs, const unsigned int* __restrict__ binned,
     const float* __restrict__ dinv, const float* __restrict__ b2,
     float* __restrict__ out, int N){
  __shared__ float acc[64*40];   // 10 KB
  int t = threadIdx.x, lane = t & 63, wid = t >> 6;
  int b = blockIdx.x;
  for(int i = t; i < 2560; i += 256) acc[i] = 0.f;
  __syncthreads();
  int beg = bofs[b], end = bofs[b+1];
  int e = beg + wid;
  for(; e + 4 < end; e += 8){
    unsigned int r0 = binned[e], r1 = binned[e+4];
    if(lane < 40){
      float v0 = bf2f(g2[(size_t)(r0 & 0x1FFFFu)*40 + lane]);
      float v1 = bf2f(g2[(size_t)(r1 & 0x1FFFFu)*40 + lane]);
      atomicAdd(&acc[(r0 >> 17)*40 + lane], v0);
      atomicAdd(&acc[(r1 >> 17)*40 + lane], v1);
    }
  }
  if(e < end){
    unsigned int r0 = binned[e];
    if(lane < 40){
      float v0 = bf2f(g2[(size_t)(r0 & 0x1FFFFu)*40 + lane]);
      atomicAdd(&acc[(r0 >> 17)*40 + lane], v0);
    }
  }
  __syncthreads();
  int nodeBase = b << BUCKET_SHIFT;
  for(int ri = 0; ri < 16; ri++){
    int r = wid*16 + ri;
    int node = nodeBase + r;
    if(node >= N) continue;   // wave-uniform
    float val = -INFINITY;
    if(lane < 40){
      float self = bf2f(g2[(size_t)node*40 + lane]);
      val = dinv[node]*(acc[r*40 + lane] + self) + b2[lane];
    }
    float m = val;
    #pragma unroll
    for(int off = 32; off > 0; off >>= 1) m = fmaxf(m, __shfl_xor(m, off, 64));
    float ex = (lane < 40) ? expf(val - m) : 0.f;
    float l = ex;
    #pragma unroll
    for(int off = 32; off > 0; off >>= 1) l += __shfl_xor(l, off, 64);
    if(lane < 40) out[(size_t)node*40 + lane] = val - m - logf(l);
  }
}

// ---------------- launch ----------------

extern "C" void kernel_launch(void* const* d_in, const int* in_sizes, int n_in,
                              void* d_out, int out_size, void* d_ws, size_t ws_size,
                              hipStream_t stream){
  const float* x  = (const float*)d_in[0];
  const int*   ei = (const int*)  d_in[1];
  const float* W1 = (const float*)d_in[2];
  const float* b1 = (const float*)d_in[3];
  const float* W2 = (const float*)d_in[4];
  const float* b2 = (const float*)d_in[5];
  float* out = (float*)d_out;

  int N = in_sizes[0] / 128;        // 100000
  int E = in_sizes[1] / 2;          // 1600000
  const int* src = ei;
  const int* dst = ei + E;
  int NB = (N + NODES_PER_BUCKET - 1) >> BUCKET_SHIFT;   // 1563

  char* w = (char*)d_ws;
  auto alloc = [&](size_t bytes) -> char* {
    char* p = w;
    w += (bytes + 511) & ~(size_t)511;
    return p;
  };
  int*   cnt   = (int*)  alloc((size_t)N*4);
  float* dinv  = (float*)alloc((size_t)N*4);
  int*   bcnt  = (int*)  alloc((size_t)NB*4);
  int*   bofs  = (int*)  alloc((size_t)(NB+1)*4);
  int*   bcur  = (int*)  alloc((size_t)NB*4);
  unsigned int* binned = (unsigned int*)alloc((size_t)E*4);
  unsigned short* g1   = (unsigned short*)alloc((size_t)N*64*2);  // bf16; reused as g2
  float* out1  = (float*)alloc((size_t)N*64*4);
  unsigned short* g2   = g1;

  k_zero   <<<(N+255)/256, 256, 0, stream>>>(cnt, N);
  k_hist   <<<(E+255)/256, 256, 0, stream>>>(dst, E, cnt);
  k_dinv   <<<(N+255)/256, 256, 0, stream>>>(cnt, dinv, N);
  k_bsum   <<<(NB+255)/256, 256, 0, stream>>>(cnt, bcnt, N, NB);
  k_bscan  <<<1, 1024, 0, stream>>>(bcnt, bofs, bcur, NB, E);
  k_binpass<<<(E+BIN_CHUNK-1)/BIN_CHUNK, 256, 0, stream>>>(src, dst, E, bcur, binned, NB);

  k_gemm1  <<<(N+63)/64, 256, 0, stream>>>(x, W1, dinv, g1, N);
  k_agg1   <<<NB, 256, 0, stream>>>(g1, bofs, binned, dinv, b1, out1, N);
  k_gemm2  <<<(N+63)/64, 256, 0, stream>>>(out1, W2, dinv, g2, N);
  k_agg2   <<<NB, 256, 0, stream>>>(g2, bofs, binned, dinv, b2, out, N);
}

// Round 4
// 308.819 us; speedup vs baseline: 4.0645x; 4.0645x over previous
//
#include <hip/hip_runtime.h>
#include <math.h>

#define NPB 64            // nodes per bucket
#define BSH 6
#define MAXNB 1600
#define BIN_CHUNK 8192
#define HIST_CHUNK 16384

__device__ __forceinline__ unsigned short f2bf(float f){
  unsigned int u = __float_as_uint(f);
  unsigned int r = (u + 0x7FFFu + ((u >> 16) & 1u)) >> 16;   // RNE
  return (unsigned short)r;
}
__device__ __forceinline__ float bf2f(unsigned int b){
  return __uint_as_float(b << 16);
}

// ---------------- CSR build ----------------

__global__ void k_zero(int* __restrict__ p, int n){
  int i = blockIdx.x*256 + threadIdx.x;
  if(i < n) p[i] = 0;
}

// bucket histogram: LDS-staged, few global atomics (196 per address max)
__global__ __launch_bounds__(256) void k_bhist(const int* __restrict__ dst, int E,
                                               int* __restrict__ bcnt, int NB){
  __shared__ int l[MAXNB];
  int t = threadIdx.x;
  int base = blockIdx.x*HIST_CHUNK;
  int end = base + HIST_CHUNK; if(end > E) end = E;
  for(int b = t; b < NB; b += 256) l[b] = 0;
  __syncthreads();
  for(int i = base + t; i < end; i += 256) atomicAdd(&l[dst[i] >> BSH], 1);
  __syncthreads();
  for(int b = t; b < NB; b += 256){ int c = l[b]; if(c) atomicAdd(&bcnt[b], c); }
}

// single-block scan over NB (<=2048) bucket counts -> bofs (exclusive), bcur
__global__ void k_bscan(const int* __restrict__ bcnt, int* __restrict__ bofs,
                        int* __restrict__ bcur, int NB, int E){
  __shared__ int sh[1024];
  int t = threadIdx.x;
  int c0 = (2*t   < NB) ? bcnt[2*t]   : 0;
  int c1 = (2*t+1 < NB) ? bcnt[2*t+1] : 0;
  sh[t] = c0 + c1; __syncthreads();
  for(int off = 1; off < 1024; off <<= 1){
    int v = (t >= off) ? sh[t - off] : 0;
    __syncthreads();
    sh[t] += v;
    __syncthreads();
  }
  int pairEx = sh[t] - (c0 + c1);
  if(2*t   < NB){ bofs[2*t]   = pairEx;      bcur[2*t]   = pairEx; }
  if(2*t+1 < NB){ bofs[2*t+1] = pairEx + c0; bcur[2*t+1] = pairEx + c0; }
  if(t == 0) bofs[NB] = E;
}

// LDS-staged binning (per-block hist -> one range reservation per bucket -> burst writes)
__global__ __launch_bounds__(256) void k_binpass(const int* __restrict__ src,
                          const int* __restrict__ dst, int E,
                          int* __restrict__ bcur, unsigned int* __restrict__ binned, int NB){
  __shared__ int lcnt[MAXNB];
  __shared__ int lpos[MAXNB];
  int t = threadIdx.x;
  int base = blockIdx.x * BIN_CHUNK;
  int end = base + BIN_CHUNK; if(end > E) end = E;
  for(int b = t; b < NB; b += 256) lcnt[b] = 0;
  __syncthreads();
  for(int i = base + t; i < end; i += 256)
    atomicAdd(&lcnt[dst[i] >> BSH], 1);
  __syncthreads();
  for(int b = t; b < NB; b += 256){
    int c = lcnt[b];
    lpos[b] = c ? atomicAdd(&bcur[b], c) : 0;
  }
  __syncthreads();
  for(int i = base + t; i < end; i += 256){
    int d = dst[i];
    int b = d >> BSH;
    unsigned int rec = (unsigned int)src[i] | ((unsigned int)(d & (NPB-1)) << 17);
    int p = atomicAdd(&lpos[b], 1);
    binned[p] = rec;
  }
}

// one block per bucket: local 64-node hist + wave scan -> row_ofs, dinv, csr (dst-sorted)
__global__ __launch_bounds__(256) void k_bscatter(const unsigned int* __restrict__ binned,
     const int* __restrict__ bofs, int* __restrict__ csr, int* __restrict__ row_ofs,
     float* __restrict__ dinv, int N, int E, int NB){
  __shared__ int lcnt[NPB];
  __shared__ int lofs[NPB];
  __shared__ int lcur[NPB];
  int b = blockIdx.x, t = threadIdx.x;
  int beg = bofs[b], end = bofs[b+1];
  if(t < NPB) lcnt[t] = 0;
  __syncthreads();
  for(int i = beg + t; i < end; i += 256) atomicAdd(&lcnt[binned[i] >> 17], 1);
  __syncthreads();
  if(t < NPB){   // wave 0 only
    int c = lcnt[t];
    int v = c;
    #pragma unroll
    for(int off = 1; off < 64; off <<= 1){
      int nv = __shfl_up(v, off, 64);
      if(t >= off) v += nv;
    }
    int ex = v - c;
    lofs[t] = beg + ex; lcur[t] = 0;
    int node = (b << BSH) + t;
    if(node < N){
      row_ofs[node] = beg + ex;
      dinv[node] = rsqrtf((float)(c + 1));   // +1 self loop
    }
  }
  __syncthreads();
  for(int i = beg + t; i < end; i += 256){
    unsigned int rec = binned[i];
    int dl = rec >> 17;
    int pos = lofs[dl] + atomicAdd(&lcur[dl], 1);
    csr[pos] = (int)(rec & 0x1FFFFu);
  }
  if(b == NB-1 && t == 0) row_ofs[N] = E;
}

// ---------------- GEMM1: g1 = bf16( dinv * (x @ W1) ) ----------------
__global__ __launch_bounds__(256) void k_gemm1(const float* __restrict__ x, const float* __restrict__ W1,
                        const float* __restrict__ dinv, unsigned short* __restrict__ g1, int n){
  __shared__ float xs[64*128];
  __shared__ float ws[128*64];
  int tid = threadIdx.x;
  int nodeBase = blockIdx.x*64;
  {
    const float4* w4 = (const float4*)W1;
    float4* s4 = (float4*)ws;
    for(int i = tid; i < 2048; i += 256) s4[i] = w4[i];
  }
  {
    const float4* x4 = (const float4*)x;
    float4* s4 = (float4*)xs;
    for(int i = tid; i < 2048; i += 256){
      int node = i >> 5, kg = i & 31;
      float4 v = make_float4(0.f,0.f,0.f,0.f);
      if(nodeBase + node < n) v = x4[(size_t)(nodeBase + node)*32 + kg];
      s4[i] = v;
    }
  }
  __syncthreads();
  int tx = tid & 7, ty = tid >> 3;
  int n0 = ty*2, f0 = tx*8;
  float acc[2][8];
  #pragma unroll
  for(int i = 0; i < 2; i++)
    #pragma unroll
    for(int j = 0; j < 8; j++) acc[i][j] = 0.f;

  #pragma unroll 4
  for(int k = 0; k < 128; k++){
    float a0 = xs[(n0+0)*128 + k];
    float a1 = xs[(n0+1)*128 + k];
    float4 b0 = *(const float4*)&ws[k*64 + f0];
    float4 b1 = *(const float4*)&ws[k*64 + f0 + 4];
    acc[0][0] += a0*b0.x; acc[0][1] += a0*b0.y; acc[0][2] += a0*b0.z; acc[0][3] += a0*b0.w;
    acc[0][4] += a0*b1.x; acc[0][5] += a0*b1.y; acc[0][6] += a0*b1.z; acc[0][7] += a0*b1.w;
    acc[1][0] += a1*b0.x; acc[1][1] += a1*b0.y; acc[1][2] += a1*b0.z; acc[1][3] += a1*b0.w;
    acc[1][4] += a1*b1.x; acc[1][5] += a1*b1.y; acc[1][6] += a1*b1.z; acc[1][7] += a1*b1.w;
  }
  #pragma unroll
  for(int i = 0; i < 2; i++){
    int node = nodeBase + n0 + i;
    if(node < n){
      float dv = dinv[node];
      union { unsigned short us[8]; uint4 u4; } pk;
      #pragma unroll
      for(int j = 0; j < 8; j++) pk.us[j] = f2bf(acc[i][j]*dv);
      *(uint4*)&g1[(size_t)node*64 + f0] = pk.u4;
    }
  }
}

// ---------------- agg1: wave/node CSR, shfl index batches, 8 gathers in flight ----------------
// u = bf16( dinv * relu( dinv*(g1_self + sum g1[src]) + b1 ) )
__global__ __launch_bounds__(256) void k_agg1(const unsigned short* __restrict__ g1,
    const int* __restrict__ row_ofs, const int* __restrict__ csr,
    const float* __restrict__ dinv, const float* __restrict__ b1,
    unsigned short* __restrict__ u, int N){
  int wid = threadIdx.x >> 6, lane = threadIdx.x & 63;
  int node = blockIdx.x*4 + wid;
  if(node >= N) return;
  int beg = row_ofs[node], end = row_ofs[node+1];
  float s = bf2f(g1[(size_t)node*64 + lane]);   // self loop
  for(int e = beg; e < end; e += 64){
    int cnt = end - e; if(cnt > 64) cnt = 64;
    int idx = (e + lane < end) ? csr[e + lane] : 0;   // one coalesced load = 64 indices
    for(int j = 0; j < cnt; j += 8){
      int i0=__shfl(idx,j+0), i1=__shfl(idx,j+1), i2=__shfl(idx,j+2), i3=__shfl(idx,j+3);
      int i4=__shfl(idx,j+4), i5=__shfl(idx,j+5), i6=__shfl(idx,j+6), i7=__shfl(idx,j+7);
      float v0=bf2f(g1[(size_t)i0*64+lane]), v1=bf2f(g1[(size_t)i1*64+lane]);
      float v2=bf2f(g1[(size_t)i2*64+lane]), v3=bf2f(g1[(size_t)i3*64+lane]);
      float v4=bf2f(g1[(size_t)i4*64+lane]), v5=bf2f(g1[(size_t)i5*64+lane]);
      float v6=bf2f(g1[(size_t)i6*64+lane]), v7=bf2f(g1[(size_t)i7*64+lane]);
      float w0=(j+0<cnt)?1.f:0.f, w1=(j+1<cnt)?1.f:0.f, w2=(j+2<cnt)?1.f:0.f, w3=(j+3<cnt)?1.f:0.f;
      float w4=(j+4<cnt)?1.f:0.f, w5=(j+5<cnt)?1.f:0.f, w6=(j+6<cnt)?1.f:0.f, w7=(j+7<cnt)?1.f:0.f;
      s = fmaf(v0,w0, fmaf(v1,w1, fmaf(v2,w2, fmaf(v3,w3,
          fmaf(v4,w4, fmaf(v5,w5, fmaf(v6,w6, fmaf(v7,w7, s))))))));
    }
  }
  float dv = dinv[node];
  float h = fmaxf(dv*s + b1[lane], 0.f);
  u[(size_t)node*64 + lane] = f2bf(dv*h);
}

// ---------------- GEMM2: g2 = bf16( u @ W2 ), rows padded to 64 ----------------
__global__ __launch_bounds__(256) void k_gemm2(const unsigned short* __restrict__ u,
                        const float* __restrict__ W2, unsigned short* __restrict__ g2, int n){
  __shared__ float hs[64*65];
  __shared__ float ws[64*40];
  int t = threadIdx.x;
  int nodeBase = blockIdx.x*64;
  for(int i = t; i < 2560; i += 256) ws[i] = W2[i];
  for(int i = t; i < 512; i += 256){       // 64 rows x 8 segs of 8 bf16
    int row = i >> 3, seg = i & 7;
    uint4 v = make_uint4(0,0,0,0);
    if(nodeBase + row < n) v = *(const uint4*)&u[(size_t)(nodeBase + row)*64 + seg*8];
    float* dp = &hs[row*65 + seg*8];
    dp[0]=bf2f(v.x&0xFFFFu); dp[1]=bf2f(v.x>>16);
    dp[2]=bf2f(v.y&0xFFFFu); dp[3]=bf2f(v.y>>16);
    dp[4]=bf2f(v.z&0xFFFFu); dp[5]=bf2f(v.z>>16);
    dp[6]=bf2f(v.w&0xFFFFu); dp[7]=bf2f(v.w>>16);
  }
  __syncthreads();
  int tn = t >> 3, tf = t & 7;
  int n0 = tn*2, f0 = tf*5;
  float a2[2][5] = {{0.f,0.f,0.f,0.f,0.f},{0.f,0.f,0.f,0.f,0.f}};
  #pragma unroll 4
  for(int k = 0; k < 64; k++){
    float a0 = hs[(n0+0)*65 + k];
    float a1 = hs[(n0+1)*65 + k];
    float w0 = ws[k*40+f0+0], w1 = ws[k*40+f0+1], w2 = ws[k*40+f0+2],
          w3 = ws[k*40+f0+3], w4 = ws[k*40+f0+4];
    a2[0][0]+=a0*w0; a2[0][1]+=a0*w1; a2[0][2]+=a0*w2; a2[0][3]+=a0*w3; a2[0][4]+=a0*w4;
    a2[1][0]+=a1*w0; a2[1][1]+=a1*w1; a2[1][2]+=a1*w2; a2[1][3]+=a1*w3; a2[1][4]+=a1*w4;
  }
  #pragma unroll
  for(int i = 0; i < 2; i++){
    int node = nodeBase + n0 + i;
    if(node < n){
      #pragma unroll
      for(int j = 0; j < 5; j++)
        g2[(size_t)node*64 + f0 + j] = f2bf(a2[i][j]);
    }
  }
}

// ---------------- agg2 + bias + log_softmax (same gather structure as agg1) ----------------
__global__ __launch_bounds__(256) void k_agg2(const unsigned short* __restrict__ g2,
     const int* __restrict__ row_ofs, const int* __restrict__ csr,
     const float* __restrict__ dinv, const float* __restrict__ b2,
     float* __restrict__ out, int N){
  int wid = threadIdx.x >> 6, lane = threadIdx.x & 63;
  int node = blockIdx.x*4 + wid;
  if(node >= N) return;
  int beg = row_ofs[node], end = row_ofs[node+1];
  float s = bf2f(g2[(size_t)node*64 + lane]);   // lanes>=40 accumulate garbage, discarded
  for(int e = beg; e < end; e += 64){
    int cnt = end - e; if(cnt > 64) cnt = 64;
    int idx = (e + lane < end) ? csr[e + lane] : 0;
    for(int j = 0; j < cnt; j += 8){
      int i0=__shfl(idx,j+0), i1=__shfl(idx,j+1), i2=__shfl(idx,j+2), i3=__shfl(idx,j+3);
      int i4=__shfl(idx,j+4), i5=__shfl(idx,j+5), i6=__shfl(idx,j+6), i7=__shfl(idx,j+7);
      float v0=bf2f(g2[(size_t)i0*64+lane]), v1=bf2f(g2[(size_t)i1*64+lane]);
      float v2=bf2f(g2[(size_t)i2*64+lane]), v3=bf2f(g2[(size_t)i3*64+lane]);
      float v4=bf2f(g2[(size_t)i4*64+lane]), v5=bf2f(g2[(size_t)i5*64+lane]);
      float v6=bf2f(g2[(size_t)i6*64+lane]), v7=bf2f(g2[(size_t)i7*64+lane]);
      float w0=(j+0<cnt)?1.f:0.f, w1=(j+1<cnt)?1.f:0.f, w2=(j+2<cnt)?1.f:0.f, w3=(j+3<cnt)?1.f:0.f;
      float w4=(j+4<cnt)?1.f:0.f, w5=(j+5<cnt)?1.f:0.f, w6=(j+6<cnt)?1.f:0.f, w7=(j+7<cnt)?1.f:0.f;
      s = fmaf(v0,w0, fmaf(v1,w1, fmaf(v2,w2, fmaf(v3,w3,
          fmaf(v4,w4, fmaf(v5,w5, fmaf(v6,w6, fmaf(v7,w7, s))))))));
    }
  }
  float val = -INFINITY;
  if(lane < 40) val = dinv[node]*s + b2[lane];
  float m = val;
  #pragma unroll
  for(int off = 32; off > 0; off >>= 1) m = fmaxf(m, __shfl_xor(m, off, 64));
  float ex = (lane < 40) ? expf(val - m) : 0.f;
  float l = ex;
  #pragma unroll
  for(int off = 32; off > 0; off >>= 1) l += __shfl_xor(l, off, 64);
  if(lane < 40) out[(size_t)node*40 + lane] = val - m - logf(l);
}

// ---------------- launch ----------------

extern "C" void kernel_launch(void* const* d_in, const int* in_sizes, int n_in,
                              void* d_out, int out_size, void* d_ws, size_t ws_size,
                              hipStream_t stream){
  const float* x  = (const float*)d_in[0];
  const int*   ei = (const int*)  d_in[1];
  const float* W1 = (const float*)d_in[2];
  const float* b1 = (const float*)d_in[3];
  const float* W2 = (const float*)d_in[4];
  const float* b2 = (const float*)d_in[5];
  float* out = (float*)d_out;

  int N = in_sizes[0] / 128;        // 100000
  int E = in_sizes[1] / 2;          // 1600000
  const int* src = ei;
  const int* dst = ei + E;
  int NB = (N + NPB - 1) >> BSH;    // 1563

  char* w = (char*)d_ws;
  auto alloc = [&](size_t bytes) -> char* {
    char* p = w;
    w += (bytes + 511) & ~(size_t)511;
    return p;
  };
  int*   bcnt    = (int*)  alloc((size_t)NB*4);
  int*   bofs    = (int*)  alloc((size_t)(NB+1)*4);
  int*   bcur    = (int*)  alloc((size_t)NB*4);
  int*   row_ofs = (int*)  alloc((size_t)(N+1)*4);
  float* dinv    = (float*)alloc((size_t)N*4);
  unsigned int* binned = (unsigned int*)alloc((size_t)E*4);
  int*   csr     = (int*)  alloc((size_t)E*4);
  unsigned short* g1 = (unsigned short*)alloc((size_t)N*64*2);
  unsigned short* u  = (unsigned short*)alloc((size_t)N*64*2);
  unsigned short* g2 = (unsigned short*)alloc((size_t)N*64*2);

  k_zero    <<<(NB+255)/256, 256, 0, stream>>>(bcnt, NB);
  k_bhist   <<<(E+HIST_CHUNK-1)/HIST_CHUNK, 256, 0, stream>>>(dst, E, bcnt, NB);
  k_bscan   <<<1, 1024, 0, stream>>>(bcnt, bofs, bcur, NB, E);
  k_binpass <<<(E+BIN_CHUNK-1)/BIN_CHUNK, 256, 0, stream>>>(src, dst, E, bcur, binned, NB);
  k_bscatter<<<NB, 256, 0, stream>>>(binned, bofs, csr, row_ofs, dinv, N, E, NB);

  k_gemm1   <<<(N+63)/64, 256, 0, stream>>>(x, W1, dinv, g1, N);
  k_agg1    <<<(N+3)/4, 256, 0, stream>>>(g1, row_ofs, csr, dinv, b1, u, N);
  k_gemm2   <<<(N+63)/64, 256, 0, stream>>>(u, W2, g2, N);
  k_agg2    <<<(N+3)/4, 256, 0, stream>>>(g2, row_ofs, csr, dinv, b2, out, N);
}